// Round 6
// baseline (262.637 us; speedup 1.0000x reference)
//
#include <hip/hip_runtime.h>
#include <hip/hip_bf16.h>

typedef __attribute__((ext_vector_type(8))) short short8;
typedef __attribute__((ext_vector_type(4))) float f32x4;
typedef unsigned short ushort_t;

namespace {

constexpr int H     = 128;
constexpr int E     = 1000000;
constexpr int NNODE = 100000;
constexpr int EB    = 512;                   // edges per tile (16 waves x 32)
constexpr int NTILE = (E + EB - 1) / EB;     // 1954
constexpr int GRID  = 256;                   // persistent: 1 block per CU
constexpr int TPB   = NTILE / GRID;          // 7
constexpr int REM   = NTILE - TPB * GRID;    // 162 blocks do TPB+1 tiles

// d_ws layout
constexpr size_t NB_OFF  = 0;                                  // bf16 nodes: 25.6 MB
constexpr size_t W1F_OFF = (size_t)NNODE * H * 2;
constexpr size_t W1F_SZ  = 72 * 64 * 8 * 2;                    // 73728 B (K=288)
constexpr size_t W2F_OFF = W1F_OFF + W1F_SZ;
constexpr size_t W2F_SZ  = 20 * 64 * 8 * 2;                    // 20480 B (K=160)
constexpr size_t WS_NEED = W2F_OFF + W2F_SZ;

__device__ __forceinline__ ushort_t f2bf(float x) {
    unsigned u = __float_as_uint(x);
    return (ushort_t)((u + 0x7FFFu + ((u >> 16) & 1u)) >> 16);
}
__device__ __forceinline__ unsigned pkbf(float a, float b) {
    __hip_bfloat162 t = __float22bfloat162_rn(make_float2(a, b));
    return *reinterpret_cast<unsigned*>(&t);
}
__device__ __forceinline__ int imin(int a, int b) { return a < b ? a : b; }

union FragU { int4 i; short8 s; };

// ---- prep 1: node_embed fp32 -> bf16 table ----
__global__ void cvt_nodes(const float* __restrict__ src, ushort_t* __restrict__ dst, int n4) {
    int i = blockIdx.x * blockDim.x + threadIdx.x;
    int stride = gridDim.x * blockDim.x;
    for (; i < n4; i += stride) {
        float4 v = reinterpret_cast<const float4*>(src)[i];
        ushort4 o;
        o.x = f2bf(v.x); o.y = f2bf(v.y); o.z = f2bf(v.z); o.w = f2bf(v.w);
        reinterpret_cast<ushort4*>(dst)[i] = o;
    }
}

// ---- prep 2: W1ext (K=288: rows 0..255 = W1 node rows, 256/257 = attr rows, 258 = b1)
//      and W2ext (K=160: rows 0..127 = W2, 128 = b2) -> MFMA fragment layout ----
__global__ void cvt_wfrag(const float* __restrict__ W1, const float* __restrict__ b1,
                          const float* __restrict__ W2, const float* __restrict__ b2,
                          ushort_t* __restrict__ w1f, ushort_t* __restrict__ w2f) {
    int u = blockIdx.x, l = threadIdx.x;
    int lo = l & 15, hi = l >> 4;
    if (u < 72) {                       // W1ext: 9 K-steps x 8 N-tiles
        int s = u >> 3, n = u & 7, col = n * 16 + lo;
#pragma unroll
        for (int j = 0; j < 8; ++j) {
            int kk = s * 32 + hi * 8 + j;
            float v = (kk < 258) ? W1[kk * 128 + col]
                    : (kk == 258 ? b1[col] : 0.f);
            w1f[(u * 64 + l) * 8 + j] = f2bf(v);
        }
    } else {                            // W2ext: 5 K-steps x 4 N-tiles
        int u2 = u - 72;
        int s = u2 >> 2, n = u2 & 3, col = n * 16 + lo;
#pragma unroll
        for (int j = 0; j < 8; ++j) {
            int kk = s * 32 + hi * 8 + j;
            float v = (kk < 128) ? W2[kk * 64 + col]
                    : (kk == 128 ? b2[col] : 0.f);
            w2f[(u2 * 64 + l) * 8 + j] = f2bf(v);
        }
    }
}

// ---- main persistent kernel: 1024 threads, 16 waves, 4 waves/SIMD ----
struct SmemT {
    ushort_t w1f[36864];     // 73728 B
    ushort_t w2f[10240];     // 20480 B
    char     hbuf[65536];    // 16 waves x 4 KB (shared across mt halves; fenced)
    float    gs[128], bs[128], w3s[64];
};                           // 161024 B

__global__ __launch_bounds__(1024, 4)
void edge_mlp_mfma(const ushort_t* __restrict__ nb,
                   const ushort_t* __restrict__ w1fg,
                   const ushort_t* __restrict__ w2fg,
                   const int*      __restrict__ eidx,   // [2][E] int32
                   const float*    __restrict__ attr,   // [E][2]
                   const float*    __restrict__ gamma_,
                   const float*    __restrict__ beta_,
                   const float*    __restrict__ W3,
                   const float*    __restrict__ b3,
                   float*          __restrict__ out) {
    __shared__ SmemT sm;
    const int tid = threadIdx.x;
    const int bid = blockIdx.x;

    // ---- stage weights/params ONCE (full coverage with 1024 threads) ----
    {
        const uint4* s1 = reinterpret_cast<const uint4*>(w1fg);
        uint4*       d1 = reinterpret_cast<uint4*>(sm.w1f);
        for (int i = tid; i < 4608; i += 1024) d1[i] = s1[i];
        const uint4* s2 = reinterpret_cast<const uint4*>(w2fg);
        uint4*       d2 = reinterpret_cast<uint4*>(sm.w2f);
        for (int i = tid; i < 1280; i += 1024) d2[i] = s2[i];   // FIX: was if(tid<1280) -> 4KB hole
    }
    if (tid < 128) { sm.gs[tid] = gamma_[tid]; sm.bs[tid] = beta_[tid]; }
    else if (tid >= 256 && tid < 320) sm.w3s[tid - 256] = W3[tid - 256];
    __syncthreads();   // the only block-wide barrier

    const int wid = tid >> 6;
    const int lane = tid & 63;
    const int lo = lane & 15, hi = lane >> 4;
    const int ebl = wid * 32;
    const int nk = (bid < REM) ? TPB + 1 : TPB;
    char* hb = sm.hbuf + wid * 4096;
    const int xsw = (lo & 7) << 4;
    const float2* attr2 = reinterpret_cast<const float2*>(attr);
    const float b3s = b3[0];
    const f32x4 zero4 = {0.f, 0.f, 0.f, 0.f};

    // ---- tile-0 indices ----
    int ii0, ii1, ji0, ji1;
    {
        int tb = bid * EB + ebl;
        int e0 = imin(tb + lo, E - 1), e1 = imin(tb + 16 + lo, E - 1);
        ii0 = eidx[e0]; ii1 = eidx[e1];
        ji0 = eidx[E + e0]; ji1 = eidx[E + e1];
    }

    for (int k = 0; k < nk; ++k) {
        const int tb = (bid + k * GRID) * EB + ebl;

        // ---- gathers for this tile (16 b128 loads, all independent) ----
        short8 ai[2][4], aj[2][4];
#pragma unroll
        for (int s = 0; s < 4; ++s) {
            ai[0][s] = *reinterpret_cast<const short8*>(nb + (size_t)ii0 * H + s * 32 + hi * 8);
            ai[1][s] = *reinterpret_cast<const short8*>(nb + (size_t)ii1 * H + s * 32 + hi * 8);
            aj[0][s] = *reinterpret_cast<const short8*>(nb + (size_t)ji0 * H + s * 32 + hi * 8);
            aj[1][s] = *reinterpret_cast<const short8*>(nb + (size_t)ji1 * H + s * 32 + hi * 8);
        }
        float2 av0 = attr2[imin(tb + lo, E - 1)];
        float2 av1 = attr2[imin(tb + 16 + lo, E - 1)];

        // ---- prefetch next tile's indices (4 ints, cheap) ----
        {
            int kn = imin(k + 1, nk - 1);
            int tbn = (bid + kn * GRID) * EB + ebl;
            int e0 = imin(tbn + lo, E - 1), e1 = imin(tbn + 16 + lo, E - 1);
            ii0 = eidx[e0]; ii1 = eidx[e1];
            ji0 = eidx[E + e0]; ji1 = eidx[E + e1];
        }

        // ---- GEMM1 (swapped): acc[feat-tile][edge] over K=288 ----
        f32x4 acc1[2][8];
#pragma unroll
        for (int mt = 0; mt < 2; ++mt)
#pragma unroll
            for (int n = 0; n < 8; ++n) acc1[mt][n] = zero4;

#pragma unroll
        for (int s = 0; s < 4; ++s)
#pragma unroll
            for (int n = 0; n < 8; ++n) {
                short8 wa = *reinterpret_cast<const short8*>(sm.w1f + ((s * 8 + n) * 64 + lane) * 8);
                acc1[0][n] = __builtin_amdgcn_mfma_f32_16x16x32_bf16(wa, ai[0][s], acc1[0][n], 0, 0, 0);
                acc1[1][n] = __builtin_amdgcn_mfma_f32_16x16x32_bf16(wa, ai[1][s], acc1[1][n], 0, 0, 0);
            }
#pragma unroll
        for (int s = 0; s < 4; ++s)
#pragma unroll
            for (int n = 0; n < 8; ++n) {
                short8 wa = *reinterpret_cast<const short8*>(sm.w1f + (((s + 4) * 8 + n) * 64 + lane) * 8);
                acc1[0][n] = __builtin_amdgcn_mfma_f32_16x16x32_bf16(wa, aj[0][s], acc1[0][n], 0, 0, 0);
                acc1[1][n] = __builtin_amdgcn_mfma_f32_16x16x32_bf16(wa, aj[1][s], acc1[1][n], 0, 0, 0);
            }
        {   // K-step 8: attr0, attr1, bias(1.0) rows
            FragU f0, f1;
            f0.i = make_int4(hi == 0 ? (int)pkbf(av0.x, av0.y) : 0, hi == 0 ? 0x3F80 : 0, 0, 0);
            f1.i = make_int4(hi == 0 ? (int)pkbf(av1.x, av1.y) : 0, hi == 0 ? 0x3F80 : 0, 0, 0);
#pragma unroll
            for (int n = 0; n < 8; ++n) {
                short8 wa = *reinterpret_cast<const short8*>(sm.w1f + ((64 + n) * 64 + lane) * 8);
                acc1[0][n] = __builtin_amdgcn_mfma_f32_16x16x32_bf16(wa, f0.s, acc1[0][n], 0, 0, 0);
                acc1[1][n] = __builtin_amdgcn_mfma_f32_16x16x32_bf16(wa, f1.s, acc1[1][n], 0, 0, 0);
            }
        }

        // ---- per edge-half: LN -> h(LDS, swizzled) -> GEMM2 -> dot W3 -> store ----
#pragma unroll
        for (int mt = 0; mt < 2; ++mt) {
            float s1 = 0.f, s2 = 0.f;
#pragma unroll
            for (int n = 0; n < 8; ++n)
#pragma unroll
                for (int r = 0; r < 4; ++r) {
                    float x = acc1[mt][n][r];
                    s1 += x; s2 = fmaf(x, x, s2);
                }
            s1 += __shfl_xor(s1, 16); s1 += __shfl_xor(s1, 32);
            s2 += __shfl_xor(s2, 16); s2 += __shfl_xor(s2, 32);
            float mean = s1 * (1.f / 128.f);
            float var  = s2 * (1.f / 128.f) - mean * mean;
            float rstd = rsqrtf(var + 1e-5f);

            // WAR fence: prior GEMM2 ds_reads (this wave) must complete before
            // overwriting the shared h buffer; also blocks compiler motion (rule #18).
            asm volatile("s_waitcnt lgkmcnt(0)" ::: "memory");
            __builtin_amdgcn_sched_barrier(0);

            char* hmt = hb + lo * 256;
#pragma unroll
            for (int n = 0; n < 8; ++n) {
                f32x4 gv = *reinterpret_cast<const f32x4*>(sm.gs + n * 16 + hi * 4);
                f32x4 bv = *reinterpret_cast<const f32x4*>(sm.bs + n * 16 + hi * 4);
                float h0 = fmaxf(fmaf((acc1[mt][n][0] - mean) * rstd, gv[0], bv[0]), 0.f);
                float h1 = fmaxf(fmaf((acc1[mt][n][1] - mean) * rstd, gv[1], bv[1]), 0.f);
                float h2 = fmaxf(fmaf((acc1[mt][n][2] - mean) * rstd, gv[2], bv[2]), 0.f);
                float h3 = fmaxf(fmaf((acc1[mt][n][3] - mean) * rstd, gv[3], bv[3]), 0.f);
                *reinterpret_cast<uint2*>(hmt + ((hi * 8 + n * 32) ^ xsw)) =
                    make_uint2(pkbf(h0, h1), pkbf(h2, h3));
            }

            // GEMM2 (swapped): acc2[col2-tile][edge] over K=160
            f32x4 a2[4];
#pragma unroll
            for (int n2 = 0; n2 < 4; ++n2) a2[n2] = zero4;
#pragma unroll
            for (int s = 0; s < 4; ++s) {
                short8 hf = *reinterpret_cast<const short8*>(hmt + ((s * 64 + hi * 16) ^ xsw));
#pragma unroll
                for (int n2 = 0; n2 < 4; ++n2) {
                    short8 wa = *reinterpret_cast<const short8*>(sm.w2f + ((s * 4 + n2) * 64 + lane) * 8);
                    a2[n2] = __builtin_amdgcn_mfma_f32_16x16x32_bf16(wa, hf, a2[n2], 0, 0, 0);
                }
            }
            {   // K-step 4: bias row (b2)
                FragU cf; cf.i = make_int4(hi == 0 ? 0x3F80 : 0, 0, 0, 0);
#pragma unroll
                for (int n2 = 0; n2 < 4; ++n2) {
                    short8 wa = *reinterpret_cast<const short8*>(sm.w2f + ((16 + n2) * 64 + lane) * 8);
                    a2[n2] = __builtin_amdgcn_mfma_f32_16x16x32_bf16(wa, cf.s, a2[n2], 0, 0, 0);
                }
            }

            // epilogue: relu, dot W3 (from LDS), cross-hi reduce, store
            float part = 0.f;
#pragma unroll
            for (int n2 = 0; n2 < 4; ++n2) {
                f32x4 w3v = *reinterpret_cast<const f32x4*>(sm.w3s + n2 * 16 + hi * 4);
#pragma unroll
                for (int r = 0; r < 4; ++r)
                    part = fmaf(fmaxf(a2[n2][r], 0.f), w3v[r], part);
            }
            part += __shfl_xor(part, 16);
            part += __shfl_xor(part, 32);
            if (hi == 0) {
                int e = tb + mt * 16 + lo;
                if (e < E) out[e] = part + b3s;
            }
        }
    }
}

} // namespace

extern "C" void kernel_launch(void* const* d_in, const int* in_sizes, int n_in,
                              void* d_out, int out_size, void* d_ws, size_t ws_size,
                              hipStream_t stream) {
    const float* node_embed = (const float*)d_in[0];
    const int*   eidx       = (const int*)  d_in[1];
    const float* attr       = (const float*)d_in[2];
    const float* W1         = (const float*)d_in[3];
    const float* b1         = (const float*)d_in[4];
    const float* gamma      = (const float*)d_in[5];
    const float* beta       = (const float*)d_in[6];
    const float* W2         = (const float*)d_in[7];
    const float* b2         = (const float*)d_in[8];
    const float* W3         = (const float*)d_in[9];
    const float* b3         = (const float*)d_in[10];
    float* out = (float*)d_out;

    if (ws_size < WS_NEED) return;

    char* ws = (char*)d_ws;
    ushort_t* nbf = (ushort_t*)(ws + NB_OFF);
    ushort_t* w1f = (ushort_t*)(ws + W1F_OFF);
    ushort_t* w2f = (ushort_t*)(ws + W2F_OFF);

    cvt_nodes<<<2048, 256, 0, stream>>>(node_embed, nbf, NNODE * H / 4);
    cvt_wfrag<<<92, 64, 0, stream>>>(W1, b1, W2, b2, w1f, w2f);
    edge_mlp_mfma<<<GRID, 1024, 0, stream>>>(nbf, w1f, w2f, eidx, attr,
                                             gamma, beta, W3, b3, out);
}

// Round 7
// 256.961 us; speedup vs baseline: 1.0221x; 1.0221x over previous
//
#include <hip/hip_runtime.h>
#include <hip/hip_bf16.h>

typedef __attribute__((ext_vector_type(8))) short short8;
typedef __attribute__((ext_vector_type(4))) float f32x4;
typedef unsigned short ushort_t;

namespace {

constexpr int H     = 128;
constexpr int E     = 1000000;
constexpr int NNODE = 100000;
constexpr int EB    = 512;                   // edges per tile (16 waves x 32)
constexpr int NTILE = (E + EB - 1) / EB;     // 1954
constexpr int GRID  = 256;                   // persistent: 1 block per CU
constexpr int TPB   = NTILE / GRID;          // 7
constexpr int REM   = NTILE - TPB * GRID;    // 162 blocks do TPB+1 tiles

// d_ws layout
constexpr size_t NB_OFF  = 0;                                  // bf16 nodes: 25.6 MB
constexpr size_t W1F_OFF = (size_t)NNODE * H * 2;
constexpr size_t W1F_SZ  = 72 * 64 * 8 * 2;                    // 73728 B (K=288)
constexpr size_t W2F_OFF = W1F_OFF + W1F_SZ;
constexpr size_t W2F_SZ  = 20 * 64 * 8 * 2;                    // 20480 B (K=160)
constexpr size_t WS_NEED = W2F_OFF + W2F_SZ;

__device__ __forceinline__ ushort_t f2bf(float x) {
    unsigned u = __float_as_uint(x);
    return (ushort_t)((u + 0x7FFFu + ((u >> 16) & 1u)) >> 16);
}
__device__ __forceinline__ unsigned pkbf(float a, float b) {
    __hip_bfloat162 t = __float22bfloat162_rn(make_float2(a, b));
    return *reinterpret_cast<unsigned*>(&t);
}
__device__ __forceinline__ int imin(int a, int b) { return a < b ? a : b; }

union FragU { int4 i; short8 s; };

// ---- prep 1: node_embed fp32 -> bf16 table ----
__global__ void cvt_nodes(const float* __restrict__ src, ushort_t* __restrict__ dst, int n4) {
    int i = blockIdx.x * blockDim.x + threadIdx.x;
    int stride = gridDim.x * blockDim.x;
    for (; i < n4; i += stride) {
        float4 v = reinterpret_cast<const float4*>(src)[i];
        ushort4 o;
        o.x = f2bf(v.x); o.y = f2bf(v.y); o.z = f2bf(v.z); o.w = f2bf(v.w);
        reinterpret_cast<ushort4*>(dst)[i] = o;
    }
}

// ---- prep 2: W1ext (K=288: rows 0..255 = W1 node rows, 256/257 = attr rows, 258 = b1)
//      and W2ext (K=160: rows 0..127 = W2, 128 = b2) -> MFMA fragment layout ----
__global__ void cvt_wfrag(const float* __restrict__ W1, const float* __restrict__ b1,
                          const float* __restrict__ W2, const float* __restrict__ b2,
                          ushort_t* __restrict__ w1f, ushort_t* __restrict__ w2f) {
    int u = blockIdx.x, l = threadIdx.x;
    int lo = l & 15, hi = l >> 4;
    if (u < 72) {                       // W1ext: 9 K-steps x 8 N-tiles
        int s = u >> 3, n = u & 7, col = n * 16 + lo;
#pragma unroll
        for (int j = 0; j < 8; ++j) {
            int kk = s * 32 + hi * 8 + j;
            float v = (kk < 258) ? W1[kk * 128 + col]
                    : (kk == 258 ? b1[col] : 0.f);
            w1f[(u * 64 + l) * 8 + j] = f2bf(v);
        }
    } else {                            // W2ext: 5 K-steps x 4 N-tiles
        int u2 = u - 72;
        int s = u2 >> 2, n = u2 & 3, col = n * 16 + lo;
#pragma unroll
        for (int j = 0; j < 8; ++j) {
            int kk = s * 32 + hi * 8 + j;
            float v = (kk < 128) ? W2[kk * 64 + col]
                    : (kk == 128 ? b2[col] : 0.f);
            w2f[(u2 * 64 + l) * 8 + j] = f2bf(v);
        }
    }
}

// ---- main persistent kernel: 1024 threads, 16 waves, 4 waves/SIMD ----
struct SmemT {
    ushort_t w1f[36864];     // 73728 B
    ushort_t w2f[10240];     // 20480 B
    char     hbuf[65536];    // 16 waves x 4 KB (fragment-linear h; shared across mt)
    float    gs[128], bs[128], w3s[64];
};                           // 161024 B

__global__ __launch_bounds__(1024, 4)
void edge_mlp_mfma(const ushort_t* __restrict__ nb,
                   const ushort_t* __restrict__ w1fg,
                   const ushort_t* __restrict__ w2fg,
                   const int*      __restrict__ eidx,   // [2][E] int32
                   const float*    __restrict__ attr,   // [E][2]
                   const float*    __restrict__ gamma_,
                   const float*    __restrict__ beta_,
                   const float*    __restrict__ W3,
                   const float*    __restrict__ b3,
                   float*          __restrict__ out) {
    __shared__ SmemT sm;
    const int tid = threadIdx.x;
    const int bid = blockIdx.x;

    // ---- stage weights/params ONCE (full coverage with 1024 threads) ----
    {
        const uint4* s1 = reinterpret_cast<const uint4*>(w1fg);
        uint4*       d1 = reinterpret_cast<uint4*>(sm.w1f);
        for (int i = tid; i < 4608; i += 1024) d1[i] = s1[i];
        const uint4* s2 = reinterpret_cast<const uint4*>(w2fg);
        uint4*       d2 = reinterpret_cast<uint4*>(sm.w2f);
        for (int i = tid; i < 1280; i += 1024) d2[i] = s2[i];
    }
    if (tid < 128) { sm.gs[tid] = gamma_[tid]; sm.bs[tid] = beta_[tid]; }
    else if (tid >= 256 && tid < 320) sm.w3s[tid - 256] = W3[tid - 256];
    __syncthreads();   // the only block-wide barrier

    const int wid = tid >> 6;
    const int lane = tid & 63;
    const int lo = lane & 15, hi = lane >> 4;
    const int ebl = wid * 32;
    const int nk = (bid < REM) ? TPB + 1 : TPB;
    char* hb = sm.hbuf + wid * 4096;
    const float2* attr2 = reinterpret_cast<const float2*>(attr);
    const float b3s = b3[0];
    const f32x4 zero4 = {0.f, 0.f, 0.f, 0.f};

    // fragment-linear h: element (edge, col) at byte
    //   (col>>5)*1024 + ((col&31)>>3)*256 + edge*16 + (col&7)*2
    // producer (lo,hi) writes cols n*16+hi*4+r (r=0..3) -> one b64 at:
    const int hw_base = lo * 16 + (hi & 1) * 8 + (hi >> 1) * 256;

    // ---- tile-0 indices ----
    int ii0, ii1, ji0, ji1;
    {
        int tb = bid * EB + ebl;
        int e0 = imin(tb + lo, E - 1), e1 = imin(tb + 16 + lo, E - 1);
        ii0 = eidx[e0]; ii1 = eidx[e1];
        ji0 = eidx[E + e0]; ji1 = eidx[E + e1];
    }

    for (int k = 0; k < nk; ++k) {
        const int tb = (bid + k * GRID) * EB + ebl;

        // ---- gathers for this tile (16 b128 loads, all independent) ----
        short8 ai[2][4], aj[2][4];
#pragma unroll
        for (int s = 0; s < 4; ++s) {
            ai[0][s] = *reinterpret_cast<const short8*>(nb + (size_t)ii0 * H + s * 32 + hi * 8);
            ai[1][s] = *reinterpret_cast<const short8*>(nb + (size_t)ii1 * H + s * 32 + hi * 8);
            aj[0][s] = *reinterpret_cast<const short8*>(nb + (size_t)ji0 * H + s * 32 + hi * 8);
            aj[1][s] = *reinterpret_cast<const short8*>(nb + (size_t)ji1 * H + s * 32 + hi * 8);
        }
        float2 av0 = attr2[imin(tb + lo, E - 1)];
        float2 av1 = attr2[imin(tb + 16 + lo, E - 1)];

        // ---- prefetch next tile's indices ----
        {
            int kn = imin(k + 1, nk - 1);
            int tbn = (bid + kn * GRID) * EB + ebl;
            int e0 = imin(tbn + lo, E - 1), e1 = imin(tbn + 16 + lo, E - 1);
            ii0 = eidx[e0]; ii1 = eidx[e1];
            ji0 = eidx[E + e0]; ji1 = eidx[E + e1];
        }

        // ---- GEMM1 (swapped): acc[feat-tile][edge] over K=288 ----
        f32x4 acc1[2][8];
#pragma unroll
        for (int mt = 0; mt < 2; ++mt)
#pragma unroll
            for (int n = 0; n < 8; ++n) acc1[mt][n] = zero4;

#pragma unroll
        for (int s = 0; s < 4; ++s)
#pragma unroll
            for (int n = 0; n < 8; ++n) {
                short8 wa = *reinterpret_cast<const short8*>(sm.w1f + ((s * 8 + n) * 64 + lane) * 8);
                acc1[0][n] = __builtin_amdgcn_mfma_f32_16x16x32_bf16(wa, ai[0][s], acc1[0][n], 0, 0, 0);
                acc1[1][n] = __builtin_amdgcn_mfma_f32_16x16x32_bf16(wa, ai[1][s], acc1[1][n], 0, 0, 0);
            }
#pragma unroll
        for (int s = 0; s < 4; ++s)
#pragma unroll
            for (int n = 0; n < 8; ++n) {
                short8 wa = *reinterpret_cast<const short8*>(sm.w1f + (((s + 4) * 8 + n) * 64 + lane) * 8);
                acc1[0][n] = __builtin_amdgcn_mfma_f32_16x16x32_bf16(wa, aj[0][s], acc1[0][n], 0, 0, 0);
                acc1[1][n] = __builtin_amdgcn_mfma_f32_16x16x32_bf16(wa, aj[1][s], acc1[1][n], 0, 0, 0);
            }
        {   // K-step 8: attr0, attr1, bias(1.0) rows
            FragU f0, f1;
            f0.i = make_int4(hi == 0 ? (int)pkbf(av0.x, av0.y) : 0, hi == 0 ? 0x3F80 : 0, 0, 0);
            f1.i = make_int4(hi == 0 ? (int)pkbf(av1.x, av1.y) : 0, hi == 0 ? 0x3F80 : 0, 0, 0);
#pragma unroll
            for (int n = 0; n < 8; ++n) {
                short8 wa = *reinterpret_cast<const short8*>(sm.w1f + ((64 + n) * 64 + lane) * 8);
                acc1[0][n] = __builtin_amdgcn_mfma_f32_16x16x32_bf16(wa, f0.s, acc1[0][n], 0, 0, 0);
                acc1[1][n] = __builtin_amdgcn_mfma_f32_16x16x32_bf16(wa, f1.s, acc1[1][n], 0, 0, 0);
            }
        }

        // ---- per edge-half: LN -> h(LDS, fragment-linear) -> GEMM2 -> dot W3 -> store ----
#pragma unroll
        for (int mt = 0; mt < 2; ++mt) {
            float s1 = 0.f, s2 = 0.f;
#pragma unroll
            for (int n = 0; n < 8; ++n)
#pragma unroll
                for (int r = 0; r < 4; ++r) {
                    float x = acc1[mt][n][r];
                    s1 += x; s2 = fmaf(x, x, s2);
                }
            s1 += __shfl_xor(s1, 16); s1 += __shfl_xor(s1, 32);
            s2 += __shfl_xor(s2, 16); s2 += __shfl_xor(s2, 32);
            float mean = s1 * (1.f / 128.f);
            float var  = s2 * (1.f / 128.f) - mean * mean;
            float rstd = rsqrtf(var + 1e-5f);

            // WAR fence: prior GEMM2 ds_reads (this wave) must complete before
            // overwriting the shared h buffer; also blocks compiler motion (rule #18).
            asm volatile("s_waitcnt lgkmcnt(0)" ::: "memory");
            __builtin_amdgcn_sched_barrier(0);

#pragma unroll
            for (int n = 0; n < 8; ++n) {
                f32x4 gv = *reinterpret_cast<const f32x4*>(sm.gs + n * 16 + hi * 4);
                f32x4 bv = *reinterpret_cast<const f32x4*>(sm.bs + n * 16 + hi * 4);
                float h0 = fmaxf(fmaf((acc1[mt][n][0] - mean) * rstd, gv[0], bv[0]), 0.f);
                float h1 = fmaxf(fmaf((acc1[mt][n][1] - mean) * rstd, gv[1], bv[1]), 0.f);
                float h2 = fmaxf(fmaf((acc1[mt][n][2] - mean) * rstd, gv[2], bv[2]), 0.f);
                float h3 = fmaxf(fmaf((acc1[mt][n][3] - mean) * rstd, gv[3], bv[3]), 0.f);
                *reinterpret_cast<uint2*>(hb + ((n >> 1) * 1024 + (n & 1) * 512 + hw_base)) =
                    make_uint2(pkbf(h0, h1), pkbf(h2, h3));
            }

            // GEMM2 (swapped): acc2[col2-tile][edge] over K=160
            f32x4 a2[4];
#pragma unroll
            for (int n2 = 0; n2 < 4; ++n2) a2[n2] = zero4;
#pragma unroll
            for (int s = 0; s < 4; ++s) {
                // fragment-linear read: lane-linear, conflict-free (same pattern as w1f)
                short8 hf = *reinterpret_cast<const short8*>(hb + s * 1024 + lane * 16);
#pragma unroll
                for (int n2 = 0; n2 < 4; ++n2) {
                    short8 wa = *reinterpret_cast<const short8*>(sm.w2f + ((s * 4 + n2) * 64 + lane) * 8);
                    a2[n2] = __builtin_amdgcn_mfma_f32_16x16x32_bf16(wa, hf, a2[n2], 0, 0, 0);
                }
            }
            {   // K-step 4: bias row (b2)
                FragU cf; cf.i = make_int4(hi == 0 ? 0x3F80 : 0, 0, 0, 0);
#pragma unroll
                for (int n2 = 0; n2 < 4; ++n2) {
                    short8 wa = *reinterpret_cast<const short8*>(sm.w2f + ((16 + n2) * 64 + lane) * 8);
                    a2[n2] = __builtin_amdgcn_mfma_f32_16x16x32_bf16(wa, cf.s, a2[n2], 0, 0, 0);
                }
            }

            // epilogue: relu, dot W3 (from LDS), cross-hi reduce, store
            float part = 0.f;
#pragma unroll
            for (int n2 = 0; n2 < 4; ++n2) {
                f32x4 w3v = *reinterpret_cast<const f32x4*>(sm.w3s + n2 * 16 + hi * 4);
#pragma unroll
                for (int r = 0; r < 4; ++r)
                    part = fmaf(fmaxf(a2[n2][r], 0.f), w3v[r], part);
            }
            part += __shfl_xor(part, 16);
            part += __shfl_xor(part, 32);
            if (hi == 0) {
                int e = tb + mt * 16 + lo;
                if (e < E) out[e] = part + b3s;
            }
        }
    }
}

} // namespace

extern "C" void kernel_launch(void* const* d_in, const int* in_sizes, int n_in,
                              void* d_out, int out_size, void* d_ws, size_t ws_size,
                              hipStream_t stream) {
    const float* node_embed = (const float*)d_in[0];
    const int*   eidx       = (const int*)  d_in[1];
    const float* attr       = (const float*)d_in[2];
    const float* W1         = (const float*)d_in[3];
    const float* b1         = (const float*)d_in[4];
    const float* gamma      = (const float*)d_in[5];
    const float* beta       = (const float*)d_in[6];
    const float* W2         = (const float*)d_in[7];
    const float* b2         = (const float*)d_in[8];
    const float* W3         = (const float*)d_in[9];
    const float* b3         = (const float*)d_in[10];
    float* out = (float*)d_out;

    if (ws_size < WS_NEED) return;

    char* ws = (char*)d_ws;
    ushort_t* nbf = (ushort_t*)(ws + NB_OFF);
    ushort_t* w1f = (ushort_t*)(ws + W1F_OFF);
    ushort_t* w2f = (ushort_t*)(ws + W2F_OFF);

    cvt_nodes<<<2048, 256, 0, stream>>>(node_embed, nbf, NNODE * H / 4);
    cvt_wfrag<<<92, 64, 0, stream>>>(W1, b1, W2, b2, w1f, w2f);
    edge_mlp_mfma<<<GRID, 1024, 0, stream>>>(nbf, w1f, w2f, eidx, attr,
                                             gamma, beta, W3, b3, out);
}

// Round 8
// 170.992 us; speedup vs baseline: 1.5360x; 1.5028x over previous
//
#include <hip/hip_runtime.h>
#include <hip/hip_bf16.h>

typedef __attribute__((ext_vector_type(8))) short short8;
typedef __attribute__((ext_vector_type(4))) float f32x4;
typedef unsigned short ushort_t;

namespace {

constexpr int H     = 128;
constexpr int E     = 1000000;
constexpr int NNODE = 100000;
constexpr int EB    = 512;                   // edges per tile (8 waves x 64)
constexpr int NTILE = (E + EB - 1) / EB;     // 1954
constexpr int GRID  = 256;                   // persistent: 1 block per CU
constexpr int TPB   = NTILE / GRID;          // 7
constexpr int REM   = NTILE - TPB * GRID;    // 162 blocks do TPB+1 tiles

// d_ws layout
constexpr size_t NB_OFF  = 0;                                  // bf16 nodes: 25.6 MB
constexpr size_t W1F_OFF = (size_t)NNODE * H * 2;
constexpr size_t W1F_SZ  = 72 * 64 * 8 * 2;                    // 73728 B (K=288)
constexpr size_t W2F_OFF = W1F_OFF + W1F_SZ;
constexpr size_t W2F_SZ  = 20 * 64 * 8 * 2;                    // 20480 B (K=160)
constexpr size_t WS_NEED = W2F_OFF + W2F_SZ;

__device__ __forceinline__ ushort_t f2bf(float x) {
    unsigned u = __float_as_uint(x);
    return (ushort_t)((u + 0x7FFFu + ((u >> 16) & 1u)) >> 16);
}
__device__ __forceinline__ unsigned pkbf(float a, float b) {
    __hip_bfloat162 t = __float22bfloat162_rn(make_float2(a, b));
    return *reinterpret_cast<unsigned*>(&t);
}
__device__ __forceinline__ int imin(int a, int b) { return a < b ? a : b; }

union FragU { int4 i; short8 s; };

// ---- prep 1: node_embed fp32 -> bf16 table ----
__global__ void cvt_nodes(const float* __restrict__ src, ushort_t* __restrict__ dst, int n4) {
    int i = blockIdx.x * blockDim.x + threadIdx.x;
    int stride = gridDim.x * blockDim.x;
    for (; i < n4; i += stride) {
        float4 v = reinterpret_cast<const float4*>(src)[i];
        ushort4 o;
        o.x = f2bf(v.x); o.y = f2bf(v.y); o.z = f2bf(v.z); o.w = f2bf(v.w);
        reinterpret_cast<ushort4*>(dst)[i] = o;
    }
}

// ---- prep 2: W1ext (K=288) / W2ext (K=160) -> MFMA fragment layout ----
__global__ void cvt_wfrag(const float* __restrict__ W1, const float* __restrict__ b1,
                          const float* __restrict__ W2, const float* __restrict__ b2,
                          ushort_t* __restrict__ w1f, ushort_t* __restrict__ w2f) {
    int u = blockIdx.x, l = threadIdx.x;
    int lo = l & 15, hi = l >> 4;
    if (u < 72) {                       // W1ext: 9 K-steps x 8 N-tiles
        int s = u >> 3, n = u & 7, col = n * 16 + lo;
#pragma unroll
        for (int j = 0; j < 8; ++j) {
            int kk = s * 32 + hi * 8 + j;
            float v = (kk < 258) ? W1[kk * 128 + col]
                    : (kk == 258 ? b1[col] : 0.f);
            w1f[(u * 64 + l) * 8 + j] = f2bf(v);
        }
    } else {                            // W2ext: 5 K-steps x 4 N-tiles
        int u2 = u - 72;
        int s = u2 >> 2, n = u2 & 3, col = n * 16 + lo;
#pragma unroll
        for (int j = 0; j < 8; ++j) {
            int kk = s * 32 + hi * 8 + j;
            float v = (kk < 128) ? W2[kk * 64 + col]
                    : (kk == 128 ? b2[col] : 0.f);
            w2f[(u2 * 64 + l) * 8 + j] = f2bf(v);
        }
    }
}

// ---- main persistent kernel: 512 threads, 8 waves, 64 edges/wave ----
struct SmemT {
    ushort_t w1f[36864];     // 73728 B
    ushort_t w2f[10240];     // 20480 B
    char     hbuf[65536];    // 8 waves x 8 KB (32-edge pair buffer, fenced)
    float    gs[128], bs[128], w3s[64];
};                           // 161024 B

// gather one K-slice (4 subtiles) into a named frag buffer
#define GLOAD(dst, nodes, sl)                                                              \
    _Pragma("unroll")                                                                      \
    for (int mt_ = 0; mt_ < 4; ++mt_)                                                      \
        dst[mt_] = *reinterpret_cast<const short8*>(                                       \
            nb + (size_t)nodes[mt_] * H + (sl) * 32 + hi * 8);

// one GEMM1 K-step: 8 W-fragment reads, each feeding 4 MFMAs
#define KSTEP(fbuf, sidx)                                                                  \
    _Pragma("unroll")                                                                      \
    for (int n_ = 0; n_ < 8; ++n_) {                                                       \
        short8 wa_ = *reinterpret_cast<const short8*>(                                     \
            sm.w1f + (((sidx) * 8 + n_) * 64 + lane) * 8);                                 \
        _Pragma("unroll")                                                                  \
        for (int mt_ = 0; mt_ < 4; ++mt_)                                                  \
            acc1[mt_][n_] = __builtin_amdgcn_mfma_f32_16x16x32_bf16(                       \
                wa_, fbuf[mt_], acc1[mt_][n_], 0, 0, 0);                                   \
    }

__global__ __launch_bounds__(512, 2)
void edge_mlp_mfma(const ushort_t* __restrict__ nb,
                   const ushort_t* __restrict__ w1fg,
                   const ushort_t* __restrict__ w2fg,
                   const int*      __restrict__ eidx,   // [2][E] int32
                   const float*    __restrict__ attr,   // [E][2]
                   const float*    __restrict__ gamma_,
                   const float*    __restrict__ beta_,
                   const float*    __restrict__ W3,
                   const float*    __restrict__ b3,
                   float*          __restrict__ out) {
    __shared__ SmemT sm;
    const int tid = threadIdx.x;
    const int bid = blockIdx.x;

    // ---- stage weights/params ONCE ----
    {
        const uint4* s1 = reinterpret_cast<const uint4*>(w1fg);
        uint4*       d1 = reinterpret_cast<uint4*>(sm.w1f);
        for (int i = tid; i < 4608; i += 512) d1[i] = s1[i];
        const uint4* s2 = reinterpret_cast<const uint4*>(w2fg);
        uint4*       d2 = reinterpret_cast<uint4*>(sm.w2f);
        for (int i = tid; i < 1280; i += 512) d2[i] = s2[i];
    }
    if (tid < 128) { sm.gs[tid] = gamma_[tid]; sm.bs[tid] = beta_[tid]; }
    else if (tid >= 256 && tid < 320) sm.w3s[tid - 256] = W3[tid - 256];
    __syncthreads();   // the only block-wide barrier

    const int wid = tid >> 6;
    const int lane = tid & 63;
    const int lo = lane & 15, hi = lane >> 4;
    const int ebl = wid * 64;
    const int nk = (bid < REM) ? TPB + 1 : TPB;
    char* hb = sm.hbuf + wid * 8192;
    const float2* attr2 = reinterpret_cast<const float2*>(attr);
    const float b3s = b3[0];
    const f32x4 zero4 = {0.f, 0.f, 0.f, 0.f};

    // h layout (32-edge pair buffer): element (edge e'=0..31, col) at byte
    //   (col>>5)*2048 + ((col>>3)&3)*512 + e'*16 + (col&7)*2
    const int hwb = lo * 16 + (hi & 1) * 8 + (hi >> 1) * 512;   // + half*256 + n-terms

    // ---- index state: ci/cj = tile-k indices, xi/xj = tile-(k+1) ----
    int ci[4], cj[4], xi[4], xj[4];
    {
        int tb0 = bid * EB + ebl;
#pragma unroll
        for (int mt = 0; mt < 4; ++mt) {
            int e = imin(tb0 + mt * 16 + lo, E - 1);
            ci[mt] = eidx[e]; cj[mt] = eidx[E + e];
        }
    }
    short8 f0[4], f1[4], f2[4];
    GLOAD(f0, ci, 0); GLOAD(f1, ci, 1); GLOAD(f2, ci, 2);
    {
        int tb1 = (bid + imin(1, nk - 1) * GRID) * EB + ebl;
#pragma unroll
        for (int mt = 0; mt < 4; ++mt) {
            int e = imin(tb1 + mt * 16 + lo, E - 1);
            xi[mt] = eidx[e]; xj[mt] = eidx[E + e];
        }
    }

    for (int k = 0; k < nk; ++k) {
        const int tb = (bid + k * GRID) * EB + ebl;

        float2 av[4];
#pragma unroll
        for (int mt = 0; mt < 4; ++mt)
            av[mt] = attr2[imin(tb + mt * 16 + lo, E - 1)];

        // ---- GEMM1 (swapped): acc[subtile][feat-tile], K=288, rolling gathers ----
        f32x4 acc1[4][8];
#pragma unroll
        for (int mt = 0; mt < 4; ++mt)
#pragma unroll
            for (int n = 0; n < 8; ++n) acc1[mt][n] = zero4;

        KSTEP(f0, 0); GLOAD(f0, ci, 3);
        KSTEP(f1, 1); GLOAD(f1, cj, 0);
        KSTEP(f2, 2); GLOAD(f2, cj, 1);
        KSTEP(f0, 3); GLOAD(f0, cj, 2);
        KSTEP(f1, 4); GLOAD(f1, cj, 3);
        KSTEP(f2, 5);
        KSTEP(f0, 6);
        KSTEP(f1, 7);
        {   // K-step 8: attr0, attr1, bias(1.0) rows
            FragU fa[4];
#pragma unroll
            for (int mt = 0; mt < 4; ++mt)
                fa[mt].i = make_int4(hi == 0 ? (int)pkbf(av[mt].x, av[mt].y) : 0,
                                     hi == 0 ? 0x3F80 : 0, 0, 0);
#pragma unroll
            for (int n = 0; n < 8; ++n) {
                short8 wa = *reinterpret_cast<const short8*>(sm.w1f + ((64 + n) * 64 + lane) * 8);
#pragma unroll
                for (int mt = 0; mt < 4; ++mt)
                    acc1[mt][n] = __builtin_amdgcn_mfma_f32_16x16x32_bf16(wa, fa[mt].s, acc1[mt][n], 0, 0, 0);
            }
        }

        // ---- rotate indices; issue next tile's first gather slices now so they
        //      hide under this tile's LN/GEMM2 phase ----
#pragma unroll
        for (int mt = 0; mt < 4; ++mt) { ci[mt] = xi[mt]; cj[mt] = xj[mt]; }
        GLOAD(f0, ci, 0); GLOAD(f1, ci, 1); GLOAD(f2, ci, 2);
        {
            int t2 = imin(k + 2, nk - 1);
            int tb2 = (bid + t2 * GRID) * EB + ebl;
#pragma unroll
            for (int mt = 0; mt < 4; ++mt) {
                int e = imin(tb2 + mt * 16 + lo, E - 1);
                xi[mt] = eidx[e]; xj[mt] = eidx[E + e];
            }
        }

        // ---- phase 2: two 32-edge pairs ----
#pragma unroll
        for (int p = 0; p < 2; ++p) {
            // WAR fence: previous pair's GEMM2 ds_reads must complete before
            // overwriting the shared h buffer (rule #18: pin with sched_barrier).
            asm volatile("s_waitcnt lgkmcnt(0)" ::: "memory");
            __builtin_amdgcn_sched_barrier(0);

#pragma unroll
            for (int half = 0; half < 2; ++half) {
                const int mtl = p * 2 + half;
                float s1 = 0.f, s2 = 0.f;
#pragma unroll
                for (int n = 0; n < 8; ++n)
#pragma unroll
                    for (int r = 0; r < 4; ++r) {
                        float x = acc1[mtl][n][r];
                        s1 += x; s2 = fmaf(x, x, s2);
                    }
                s1 += __shfl_xor(s1, 16); s1 += __shfl_xor(s1, 32);
                s2 += __shfl_xor(s2, 16); s2 += __shfl_xor(s2, 32);
                float mean = s1 * (1.f / 128.f);
                float var  = s2 * (1.f / 128.f) - mean * mean;
                float rstd = rsqrtf(var + 1e-5f);

#pragma unroll
                for (int n = 0; n < 8; ++n) {
                    f32x4 gv = *reinterpret_cast<const f32x4*>(sm.gs + n * 16 + hi * 4);
                    f32x4 bv = *reinterpret_cast<const f32x4*>(sm.bs + n * 16 + hi * 4);
                    float h0 = fmaxf(fmaf((acc1[mtl][n][0] - mean) * rstd, gv[0], bv[0]), 0.f);
                    float h1 = fmaxf(fmaf((acc1[mtl][n][1] - mean) * rstd, gv[1], bv[1]), 0.f);
                    float h2 = fmaxf(fmaf((acc1[mtl][n][2] - mean) * rstd, gv[2], bv[2]), 0.f);
                    float h3 = fmaxf(fmaf((acc1[mtl][n][3] - mean) * rstd, gv[3], bv[3]), 0.f);
                    *reinterpret_cast<uint2*>(hb + ((n >> 1) * 2048 + (n & 1) * 1024
                                                    + half * 256 + hwb)) =
                        make_uint2(pkbf(h0, h1), pkbf(h2, h3));
                }
            }

            // GEMM2 (swapped) on the 32-edge pair: each w2f read feeds 2 MFMAs
            f32x4 a2[2][4];
#pragma unroll
            for (int X = 0; X < 2; ++X)
#pragma unroll
                for (int n2 = 0; n2 < 4; ++n2) a2[X][n2] = zero4;

#pragma unroll
            for (int s = 0; s < 4; ++s) {
                short8 hf0 = *reinterpret_cast<const short8*>(hb + s * 2048 + hi * 512 + lo * 16);
                short8 hf1 = *reinterpret_cast<const short8*>(hb + s * 2048 + hi * 512 + 256 + lo * 16);
#pragma unroll
                for (int n2 = 0; n2 < 4; ++n2) {
                    short8 wa = *reinterpret_cast<const short8*>(sm.w2f + ((s * 4 + n2) * 64 + lane) * 8);
                    a2[0][n2] = __builtin_amdgcn_mfma_f32_16x16x32_bf16(wa, hf0, a2[0][n2], 0, 0, 0);
                    a2[1][n2] = __builtin_amdgcn_mfma_f32_16x16x32_bf16(wa, hf1, a2[1][n2], 0, 0, 0);
                }
            }
            {   // K-step 4: bias row (b2)
                FragU cf; cf.i = make_int4(hi == 0 ? 0x3F80 : 0, 0, 0, 0);
#pragma unroll
                for (int n2 = 0; n2 < 4; ++n2) {
                    short8 wa = *reinterpret_cast<const short8*>(sm.w2f + ((16 + n2) * 64 + lane) * 8);
                    a2[0][n2] = __builtin_amdgcn_mfma_f32_16x16x32_bf16(wa, cf.s, a2[0][n2], 0, 0, 0);
                    a2[1][n2] = __builtin_amdgcn_mfma_f32_16x16x32_bf16(wa, cf.s, a2[1][n2], 0, 0, 0);
                }
            }

            // epilogue: relu, dot W3, cross-hi reduce, store
#pragma unroll
            for (int X = 0; X < 2; ++X) {
                float part = 0.f;
#pragma unroll
                for (int n2 = 0; n2 < 4; ++n2) {
                    f32x4 w3v = *reinterpret_cast<const f32x4*>(sm.w3s + n2 * 16 + hi * 4);
#pragma unroll
                    for (int r = 0; r < 4; ++r)
                        part = fmaf(fmaxf(a2[X][n2][r], 0.f), w3v[r], part);
                }
                part += __shfl_xor(part, 16);
                part += __shfl_xor(part, 32);
                if (hi == 0) {
                    int e = tb + (p * 2 + X) * 16 + lo;
                    if (e < E) out[e] = part + b3s;
                }
            }
        }
    }
}

} // namespace

extern "C" void kernel_launch(void* const* d_in, const int* in_sizes, int n_in,
                              void* d_out, int out_size, void* d_ws, size_t ws_size,
                              hipStream_t stream) {
    const float* node_embed = (const float*)d_in[0];
    const int*   eidx       = (const int*)  d_in[1];
    const float* attr       = (const float*)d_in[2];
    const float* W1         = (const float*)d_in[3];
    const float* b1         = (const float*)d_in[4];
    const float* gamma      = (const float*)d_in[5];
    const float* beta       = (const float*)d_in[6];
    const float* W2         = (const float*)d_in[7];
    const float* b2         = (const float*)d_in[8];
    const float* W3         = (const float*)d_in[9];
    const float* b3         = (const float*)d_in[10];
    float* out = (float*)d_out;

    if (ws_size < WS_NEED) return;

    char* ws = (char*)d_ws;
    ushort_t* nbf = (ushort_t*)(ws + NB_OFF);
    ushort_t* w1f = (ushort_t*)(ws + W1F_OFF);
    ushort_t* w2f = (ushort_t*)(ws + W2F_OFF);

    cvt_nodes<<<2048, 256, 0, stream>>>(node_embed, nbf, NNODE * H / 4);
    cvt_wfrag<<<92, 64, 0, stream>>>(W1, b1, W2, b2, w1f, w2f);
    edge_mlp_mfma<<<GRID, 512, 0, stream>>>(nbf, w1f, w2f, eidx, attr,
                                            gamma, beta, W3, b3, out);
}